// Round 13
// baseline (136.864 us; speedup 1.0000x reference)
//
#include <hip/hip_runtime.h>
#include <hip/hip_bf16.h>

#define N 1024
#define D 64
#define H1 128
#define H2 64
#define FLAG_THRESH 0.015f
#define FLAG_CAP 256    // flags/block: Binomial(512, ~0.0075), mean ~3.8
#define H1PAD 136       // f16 LDS row stride: 272 B (b128-aligned, 2-way banks only)

typedef _Float16 half8 __attribute__((ext_vector_type(8)));
typedef float float4v __attribute__((ext_vector_type(4)));

// ---------------------------------------------------------------------------
// K1: pre-activations (exact f64 + f16 copies) + W2 transpose to f16.
//   A = X @ W1[:64,:] + b1   (1024 x 128)
//   B = X @ W1[64:,:]        (1024 x 128)
//   W2T[n][k] = (f16) W2[k][n]   (64 x 128, written by blocks 0..7)
// ---------------------------------------------------------------------------
__global__ __launch_bounds__(128) void precompute_kernel(
    const float* __restrict__ X, const float* __restrict__ W1,
    const float* __restrict__ b1, const float* __restrict__ W2,
    double* __restrict__ A64, double* __restrict__ B64,
    _Float16* __restrict__ A16, _Float16* __restrict__ B16,
    _Float16* __restrict__ W2T)
{
    if (blockIdx.x < 8) {       // transpose W2 once (8 blocks x 128 thr x 8 elems)
        #pragma unroll
        for (int e = 0; e < 8; ++e) {
            int idx = blockIdx.x * 1024 + threadIdx.x * 8 + e;   // 0..8191
            int n = idx >> 7, k = idx & 127;
            W2T[idx] = (_Float16)W2[k * H2 + n];
        }
    }
    int i = blockIdx.x;
    int k = threadIdx.x;
    double a = (double)b1[k];
    double b = 0.0;
    for (int c = 0; c < D; ++c) {
        double x = (double)X[i * D + c];              // wave-uniform
        a += x * (double)W1[c * H1 + k];
        b += x * (double)W1[(D + c) * H1 + k];
    }
    A64[i * H1 + k] = a;
    B64[i * H1 + k] = b;
    A16[i * H1 + k] = (_Float16)(float)a;
    B16[i * H1 + k] = (_Float16)(float)b;
}

// ---------------------------------------------------------------------------
// K2: FUSED symmetric pair-MLP + gumbel + f64 repair. 16x16 pair tiles,
// 2080 triangular blocks (ti <= tj), ~20.7 KB LDS (no W2 stage; no dmat).
//   - afrag (A-operand = W2) loaded from pre-transposed global W2T, lives in
//     64 VGPRs for the block (proven resident under (256,3) — R9/R12)
//   - wave = (dir, row-half); hb loaded once per wave, reused over 8 rows
//   - symmetrize via 16x17 LDS bufs; repair h1s overlays Ar after barrier
// ---------------------------------------------------------------------------
__global__ __launch_bounds__(256, 3) void fused_pair_kernel(
    const _Float16* __restrict__ A16, const _Float16* __restrict__ B16,
    const _Float16* __restrict__ W2T,
    const double* __restrict__ A64, const double* __restrict__ B64,
    const float* __restrict__ W2, const float* __restrict__ b2,
    const float* __restrict__ W3, const float* __restrict__ b3,
    const float* __restrict__ u, float* __restrict__ out)
{
    __shared__ __align__(16) _Float16 Ar[32 * H1PAD];  // rows 0-15: A16[I], 16-31: A16[J]
    __shared__ __align__(16) _Float16 Br[32 * H1PAD];  // rows 0-15: B16[I], 16-31: B16[J]
    __shared__ float Sij[16][17];    // d(I_i, J_j)
    __shared__ float Sji[16][17];    // d(J_j, I_i)
    __shared__ unsigned int lflags[FLAG_CAP];
    __shared__ unsigned int lcnt;

    int tid = threadIdx.x;
    // triangular decode: 64 row-tiles -> 2080 blocks
    int t = blockIdx.x, ti = 0;
    while (t >= 64 - ti) { t -= 64 - ti; ++ti; }
    int tj = ti + t;
    int I0 = ti << 4, J0 = tj << 4;
    if (tid == 0) lcnt = 0;

    // epilogue pair indices + u prefetch (hide HBM latency under staging/GEMM)
    int i1 = tid >> 4, j1 = tid & 15;
    int ijA = (I0 + i1) * N + (J0 + j1);
    int ijB = (J0 + i1) * N + (I0 + j1);     // pass-2 pair (row J, col I)
    float2 uA = *(const float2*)&u[((size_t)ijA) * 2];
    float2 uB = *(const float2*)&u[((size_t)ijB) * 2];

    // ---- stage A/B rows (32 rows x 128 f16 each)
    #pragma unroll
    for (int itr = 0; itr < 2; ++itr) {
        int v = tid + itr * 256;         // 0..511 = 32 rows x 16 chunks
        int row = v >> 4;
        int col = (v & 15) << 3;
        int gr = (row < 16) ? (I0 + row) : (J0 + row - 16);
        *(half8*)&Ar[row * H1PAD + col] = *(const half8*)&A16[(size_t)gr * H1 + col];
        *(half8*)&Br[row * H1PAD + col] = *(const half8*)&B16[(size_t)gr * H1 + col];
    }

    int lane = tid & 63;
    int wave = tid >> 6;
    int quad = lane >> 4;                // 0..3
    int m = lane & 15;

    // ---- A-frags from global W2T (16 KB, L1-hot): 16 x dwordx4 per thread
    half8 afrag[4][4];
    #pragma unroll
    for (int ks = 0; ks < 4; ++ks)
        #pragma unroll
        for (int nt = 0; nt < 4; ++nt)
            afrag[ks][nt] = *(const half8*)&W2T[(m + 16 * nt) * H1 + quad * 8 + 32 * ks];

    // ---- per-lane layer-3 constants: o = quad*4+reg+16*nt
    float b2x[4][4], w3x[4][4];
    #pragma unroll
    for (int nt = 0; nt < 4; ++nt)
        #pragma unroll
        for (int reg = 0; reg < 4; ++reg) {
            int o = (quad << 2) + reg + (nt << 4);
            b2x[nt][reg] = b2[o];
            w3x[nt][reg] = W3[o * 2 + 1] - W3[o * 2 + 0];
        }
    __syncthreads();

    const half8 zero8 = {0, 0, 0, 0, 0, 0, 0, 0};

    // wave -> (direction, row-half). dir 0: rows=I, cols=J (S_ij);
    //                                dir 1: rows=J, cols=I (S_ji).
    int dir = wave >> 1;
    int ih = wave & 1;
    int abase = dir ? 16 : 0;
    int bbase = dir ? 0 : 16;
    float (*Sout)[17] = dir ? Sji : Sij;

    half8 hb[4];                         // this lane's column row: loaded ONCE
    #pragma unroll
    for (int ks = 0; ks < 4; ++ks)
        hb[ks] = *(const half8*)&Br[(bbase + m) * H1PAD + quad * 8 + 32 * ks];

    #pragma unroll 1
    for (int r = 0; r < 8; ++r) {
        int row = ih * 8 + r;
        float4v acc[4];
        #pragma unroll
        for (int nt = 0; nt < 4; ++nt)
            acc[nt] = (float4v){b2x[nt][0], b2x[nt][1], b2x[nt][2], b2x[nt][3]};

        #pragma unroll
        for (int ks = 0; ks < 4; ++ks) {
            half8 ha = *(const half8*)&Ar[(abase + row) * H1PAD + quad * 8 + 32 * ks]; // broadcast
            half8 h = __builtin_elementwise_max(ha + hb[ks], zero8);                   // relu
            #pragma unroll
            for (int nt = 0; nt < 4; ++nt)
                acc[nt] = __builtin_amdgcn_mfma_f32_16x16x32_f16(afrag[ks][nt], h, acc[nt], 0, 0, 0);
        }
        // fused layer 3: in-lane over 16 o's, then quad-sum via shfl_xor
        float s = 0.f;
        #pragma unroll
        for (int nt = 0; nt < 4; ++nt)
            #pragma unroll
            for (int reg = 0; reg < 4; ++reg)
                s = fmaf(fmaxf(acc[nt][reg], 0.f), w3x[nt][reg], s);
        s += __shfl_xor(s, 16, 64);
        s += __shfl_xor(s, 32, 64);
        if (quad == 0) Sout[row][m] = s;
    }
    __syncthreads();

    // ---------------- epilogue (fast __logf gumbel) ----------------
    float b3d = b3[1] - b3[0];
    {   // pass 1: out[I0+i1][J0+j1]
        float l0 = -__logf(uA.x + 1e-10f) + 1e-10f;
        float l1 = -__logf(uA.y + 1e-10f) + 1e-10f;
        float Dv = 0.5f * (Sij[i1][j1] + Sji[j1][i1]) + b3d + __logf(l0 / l1);
        out[ijA] = Dv > 0.f ? 1.f : 0.f;
        if (fabsf(Dv) < FLAG_THRESH) {
            unsigned int idx = atomicAdd(&lcnt, 1u);
            if (idx < FLAG_CAP) lflags[idx] = (unsigned int)ijA;
        }
    }
    if (ti != tj) {   // pass 2: out[J0+i1][I0+j1] (own gumbel draws)
        float l0 = -__logf(uB.x + 1e-10f) + 1e-10f;
        float l1 = -__logf(uB.y + 1e-10f) + 1e-10f;
        float Dv = 0.5f * (Sji[i1][j1] + Sij[j1][i1]) + b3d + __logf(l0 / l1);
        out[ijB] = Dv > 0.f ? 1.f : 0.f;
        if (fabsf(Dv) < FLAG_THRESH) {
            unsigned int idx = atomicAdd(&lcnt, 1u);
            if (idx < FLAG_CAP) lflags[idx] = (unsigned int)ijB;
        }
    }

    // publish lflags; drain out-stores; frees Ar for h1s overlay
    __syncthreads();

    // ---------------- repair phase (exact f64, per-wave) ----------------
    unsigned int nl = lcnt;
    if (nl > FLAG_CAP) nl = FLAG_CAP;
    double (*h1s)[2][H1] = (double(*)[2][H1])Ar;   // 4x2x128x8B = 8 KB overlay
    double w3dd = (double)W3[lane * 2 + 1] - (double)W3[lane * 2 + 0];
    double b2d = (double)b2[lane];

    for (unsigned int f = wave; f < nl; f += 4) {
        int ij = (int)lflags[f];
        int ii = ij >> 10, jj = ij & (N - 1);
        double uvd = 0.0;
        if (lane < 2) uvd = (double)u[(((size_t)ij) << 1) + lane];
        {   // lane = k (two k's per lane), coalesced f64 loads
            int k0 = lane, k1 = lane + 64;
            double ai0 = A64[(size_t)ii * H1 + k0], ai1 = A64[(size_t)ii * H1 + k1];
            double aj0 = A64[(size_t)jj * H1 + k0], aj1 = A64[(size_t)jj * H1 + k1];
            double bi0 = B64[(size_t)ii * H1 + k0], bi1 = B64[(size_t)ii * H1 + k1];
            double bj0 = B64[(size_t)jj * H1 + k0], bj1 = B64[(size_t)jj * H1 + k1];
            double v;
            v = ai0 + bj0; h1s[wave][0][k0] = v > 0.0 ? v : 0.0;
            v = ai1 + bj1; h1s[wave][0][k1] = v > 0.0 ? v : 0.0;
            v = aj0 + bi0; h1s[wave][1][k0] = v > 0.0 ? v : 0.0;
            v = aj1 + bi1; h1s[wave][1][k1] = v > 0.0 ? v : 0.0;
        }
        asm volatile("s_waitcnt lgkmcnt(0)" ::: "memory");
        __builtin_amdgcn_wave_barrier();

        // 8 independent chains: latency-hides the f64 FMA dep chain
        const double* __restrict__ hap = h1s[wave][0];
        const double* __restrict__ hbp = h1s[wave][1];
        double sa0 = 0.0, sa1 = 0.0, sa2 = 0.0, sa3 = 0.0;
        double sb0 = 0.0, sb1 = 0.0, sb2 = 0.0, sb3 = 0.0;
        #pragma unroll 2
        for (int k = 0; k < H1; k += 4) {
            double w0 = (double)W2[(k + 0) * H2 + lane];
            double w1 = (double)W2[(k + 1) * H2 + lane];
            double w2v = (double)W2[(k + 2) * H2 + lane];
            double w3v = (double)W2[(k + 3) * H2 + lane];
            sa0 += hap[k + 0] * w0;  sa1 += hap[k + 1] * w1;
            sa2 += hap[k + 2] * w2v; sa3 += hap[k + 3] * w3v;
            sb0 += hbp[k + 0] * w0;  sb1 += hbp[k + 1] * w1;
            sb2 += hbp[k + 2] * w2v; sb3 += hbp[k + 3] * w3v;
        }
        double sa = ((sa0 + sa1) + (sa2 + sa3)) + b2d;
        double sb = ((sb0 + sb1) + (sb2 + sb3)) + b2d;
        if (sa < 0.0) sa = 0.0;
        if (sb < 0.0) sb = 0.0;
        double da = sa * w3dd;
        double db = sb * w3dd;
        #pragma unroll
        for (int off = 32; off > 0; off >>= 1) {
            da += __shfl_down(da, off, 64);
            db += __shfl_down(db, off, 64);
        }
        double g = 0.0;
        if (lane < 2) g = -log(-log(uvd + 1e-10) + 1e-10);   // lanes 0,1 in parallel
        double g0 = __shfl(g, 0, 64);
        double g1 = __shfl(g, 1, 64);
        if (lane == 0) {
            double b3dd = (double)b3[1] - (double)b3[0];
            double Dv = 0.5 * (da + db) + b3dd + (g1 - g0);
            out[ij] = Dv > 0.0 ? 1.f : 0.f;
        }
        __builtin_amdgcn_wave_barrier();   // DS in-order per wave; stop reordering
    }
}

// ---------------------------------------------------------------------------
extern "C" void kernel_launch(void* const* d_in, const int* in_sizes, int n_in,
                              void* d_out, int out_size, void* d_ws, size_t ws_size,
                              hipStream_t stream) {
    const float* X  = (const float*)d_in[0];
    const float* W1 = (const float*)d_in[1];
    const float* b1 = (const float*)d_in[2];
    const float* W2 = (const float*)d_in[3];
    const float* b2 = (const float*)d_in[4];
    const float* W3 = (const float*)d_in[5];
    const float* b3 = (const float*)d_in[6];
    const float* u  = (const float*)d_in[7];
    float* out = (float*)d_out;

    // workspace layout (doubles first for alignment)
    double* A64 = (double*)d_ws;                         // 1 MB
    double* B64 = A64 + (size_t)N * H1;                  // 1 MB
    _Float16* A16 = (_Float16*)(B64 + (size_t)N * H1);   // 256 KB
    _Float16* B16 = A16 + (size_t)N * H1;                // 256 KB
    _Float16* W2T = B16 + (size_t)N * H1;                // 16 KB

    precompute_kernel<<<N, 128, 0, stream>>>(X, W1, b1, W2, A64, B64, A16, B16, W2T);
    fused_pair_kernel<<<2080, 256, 0, stream>>>(A16, B16, W2T, A64, B64,
                                                W2, b2, W3, b3, u, out);
}

// Round 14
// 131.401 us; speedup vs baseline: 1.0416x; 1.0416x over previous
//
#include <hip/hip_runtime.h>
#include <hip/hip_bf16.h>

#define N 1024
#define D 64
#define H1 128
#define H2 64
#define FLAG_THRESH 0.015f
#define FLAG_CAP 1024
#define H1PAD 136   // f16 LDS row stride: 272 B = 17*16B (b128-aligned, 2-way banks only)

typedef _Float16 half8 __attribute__((ext_vector_type(8)));
typedef float float4v __attribute__((ext_vector_type(4)));

// ---------------------------------------------------------------------------
// K1: pre-activations, exact f64 + f16 copies.
//   A = X @ W1[:64,:] + b1   (1024 x 128)
//   B = X @ W1[64:,:]        (1024 x 128)
// ---------------------------------------------------------------------------
__global__ __launch_bounds__(128) void precompute_kernel(
    const float* __restrict__ X, const float* __restrict__ W1,
    const float* __restrict__ b1,
    double* __restrict__ A64, double* __restrict__ B64,
    _Float16* __restrict__ A16, _Float16* __restrict__ B16)
{
    int i = blockIdx.x;
    int k = threadIdx.x;
    double a = (double)b1[k];
    double b = 0.0;
    for (int c = 0; c < D; ++c) {
        double x = (double)X[i * D + c];              // wave-uniform
        a += x * (double)W1[c * H1 + k];
        b += x * (double)W1[(D + c) * H1 + k];
    }
    A64[i * H1 + k] = a;
    B64[i * H1 + k] = b;
    A16[i * H1 + k] = (_Float16)(float)a;
    B16[i * H1 + k] = (_Float16)(float)b;
}

// ---------------------------------------------------------------------------
// K2: MFMA pair-MLP (R9 structure + 2x row ILP). Block = 16 i x 64 j pairs.
// OPERAND-SWAPPED GEMM: A = W2 (rows = o), B = h = relu(A16[i]+B16[j]).
// W2 staged via LDS once -> afrag resident in 64 VGPRs (R11 lesson: direct
// global afrag re-fetches; keep the stage). TWO i-rows in flight per wave:
// independent MFMA chains + reduce chains hide MFMA/VALU latency.
// ---------------------------------------------------------------------------
__global__ __launch_bounds__(256, 3) void pair_mlp_kernel(
    const _Float16* __restrict__ A16, const _Float16* __restrict__ B16,
    const float* __restrict__ W2, const float* __restrict__ b2,
    const float* __restrict__ W3, float* __restrict__ dmat)
{
    __shared__ _Float16 As16[16 * H1PAD];
    __shared__ _Float16 Bs16[64 * H1PAD];
    __shared__ _Float16 W2t[64 * H1PAD];   // transposed: W2t[n][k]

    int tid = threadIdx.x;
    int it = blockIdx.x >> 4;      // 0..63
    int jt = blockIdx.x & 15;      // 0..15
    int ti = it << 4;              // i0
    int tj = jt << 6;              // j0

    // ---- stage A16 rows (16x128 f16): 8 f16 per thread
    {
        int row = tid >> 4;
        int col = (tid & 15) << 3;
        *(half8*)&As16[row * H1PAD + col] =
            *(const half8*)&A16[(size_t)(ti + row) * H1 + col];
    }
    // ---- stage B16 rows (64x128 f16): 32 f16 per thread
    #pragma unroll
    for (int r = 0; r < 4; ++r) {
        int v = tid + r * 256;
        int row = v >> 4;
        int col = (v & 15) << 3;
        *(half8*)&Bs16[row * H1PAD + col] =
            *(const half8*)&B16[(size_t)(tj + row) * H1 + col];
    }
    // ---- stage W2 transposed to f16: W2t[n][k] = W2[k][n]
    #pragma unroll
    for (int r = 0; r < 32; ++r) {
        int idx = tid + r * 256;   // 0..8191
        int k = idx >> 6;
        int n = idx & 63;
        W2t[n * H1PAD + k] = (_Float16)W2[idx];
    }
    __syncthreads();

    int lane = tid & 63;
    int wave = tid >> 6;
    int quad = lane >> 4;          // 0..3
    int m = lane & 15;             // A-frag row (o_local) AND B-frag col (pair)

    // ---- A-frags: W2 in registers for the whole block.
    half8 afrag[4][4];
    #pragma unroll
    for (int ks = 0; ks < 4; ++ks)
        #pragma unroll
        for (int nt = 0; nt < 4; ++nt)
            afrag[ks][nt] = *(const half8*)&W2t[(m + 16 * nt) * H1PAD + quad * 8 + 32 * ks];

    // ---- per-lane layer-3 constants: o = quad*4+reg+16*nt
    float b2x[4][4], w3x[4][4];
    #pragma unroll
    for (int nt = 0; nt < 4; ++nt)
        #pragma unroll
        for (int reg = 0; reg < 4; ++reg) {
            int o = (quad << 2) + reg + (nt << 4);
            b2x[nt][reg] = b2[o];
            w3x[nt][reg] = W3[o * 2 + 1] - W3[o * 2 + 0];
        }

    const half8 zero8 = {0, 0, 0, 0, 0, 0, 0, 0};

    #pragma unroll 1
    for (int jq = 0; jq < 4; ++jq) {
        int jj0 = jq << 4;
        half8 hb[4];               // this lane's pair j = tj + jj0 + m
        #pragma unroll
        for (int ks = 0; ks < 4; ++ks)
            hb[ks] = *(const half8*)&Bs16[(jj0 + m) * H1PAD + quad * 8 + 32 * ks];

        // ---- TWO i-rows in flight: independent chains hide MFMA latency
        #pragma unroll 1
        for (int i4 = 0; i4 < 4; i4 += 2) {
            int ii0 = (wave << 2) + i4;
            int ii1 = ii0 + 1;

            float4v acc0[4], acc1[4];
            #pragma unroll
            for (int nt = 0; nt < 4; ++nt) {
                acc0[nt] = (float4v){b2x[nt][0], b2x[nt][1], b2x[nt][2], b2x[nt][3]};
                acc1[nt] = acc0[nt];
            }

            #pragma unroll
            for (int ks = 0; ks < 4; ++ks) {
                half8 ha0 = *(const half8*)&As16[ii0 * H1PAD + quad * 8 + 32 * ks];
                half8 ha1 = *(const half8*)&As16[ii1 * H1PAD + quad * 8 + 32 * ks];
                half8 h0 = __builtin_elementwise_max(ha0 + hb[ks], zero8);
                half8 h1 = __builtin_elementwise_max(ha1 + hb[ks], zero8);
                #pragma unroll
                for (int nt = 0; nt < 4; ++nt) {
                    acc0[nt] = __builtin_amdgcn_mfma_f32_16x16x32_f16(afrag[ks][nt], h0, acc0[nt], 0, 0, 0);
                    acc1[nt] = __builtin_amdgcn_mfma_f32_16x16x32_f16(afrag[ks][nt], h1, acc1[nt], 0, 0, 0);
                }
            }

            // ---- fused layer 3: two independent in-lane chains + quad-sums
            float s0 = 0.f, s1 = 0.f;
            #pragma unroll
            for (int nt = 0; nt < 4; ++nt)
                #pragma unroll
                for (int reg = 0; reg < 4; ++reg) {
                    s0 = fmaf(fmaxf(acc0[nt][reg], 0.f), w3x[nt][reg], s0);
                    s1 = fmaf(fmaxf(acc1[nt][reg], 0.f), w3x[nt][reg], s1);
                }
            s0 += __shfl_xor(s0, 16, 64);
            s1 += __shfl_xor(s1, 16, 64);
            s0 += __shfl_xor(s0, 32, 64);
            s1 += __shfl_xor(s1, 32, 64);
            if (quad == 0) {
                dmat[(size_t)(ti + ii0) * N + (tj + jj0 + m)] = s0;
                dmat[(size_t)(ti + ii1) * N + (tj + jj0 + m)] = s1;
            }
        }
    }
}

// ---------------------------------------------------------------------------
// K3: fused epilogue + f64 repair (R9-proven 32x32 tiling, 1024 blocks).
// Main: D = 0.5*(d[i][j]+d[j][i]) + b3d + log(l0/l1) (fast __logf);
// repair: per-wave, barrier-free, 8-chain f64 ILP, parallel gumbel.
// ---------------------------------------------------------------------------
__global__ __launch_bounds__(256) void epilogue_repair_kernel(
    const float* __restrict__ dmat, const double* __restrict__ A64,
    const double* __restrict__ B64, const float* __restrict__ W2,
    const float* __restrict__ b2, const float* __restrict__ W3,
    const float* __restrict__ b3, const float* __restrict__ u,
    float* __restrict__ out)
{
    __shared__ float T1[32][33];
    __shared__ float T2[32][33];
    __shared__ unsigned int lflags[FLAG_CAP];
    __shared__ unsigned int lcnt;
    __shared__ double h1s[4][2][H1];        // 8 KB, wave-private slices

    int bi = blockIdx.x >> 5;
    int bj = blockIdx.x & 31;
    int i0 = bi * 32, j0 = bj * 32;
    int tid = threadIdx.x;
    int r = tid >> 3;
    int c4 = (tid & 7) << 2;
    if (tid == 0) lcnt = 0;

    int a = tid >> 3;
    int b0 = (tid & 7) << 2;
    int ij0 = (i0 + a) * N + (j0 + b0);

    // hoisted: overlap u HBM latency with tile staging
    float4 u01 = *(const float4*)&u[((size_t)ij0) * 2];
    float4 u23 = *(const float4*)&u[((size_t)ij0) * 2 + 4];

    *(float4*)&T1[r][c4] = *(const float4*)&dmat[(size_t)(i0 + r) * N + j0 + c4];
    *(float4*)&T2[r][c4] = *(const float4*)&dmat[(size_t)(j0 + r) * N + i0 + c4];
    __syncthreads();

    float b3d = b3[1] - b3[0];
    float uu[8] = {u01.x, u01.y, u01.z, u01.w, u23.x, u23.y, u23.z, u23.w};

    float4 res;
    float* resp = &res.x;
    #pragma unroll
    for (int q = 0; q < 4; ++q) {
        int b = b0 + q;
        float l0 = -__logf(uu[2 * q] + 1e-10f) + 1e-10f;
        float l1 = -__logf(uu[2 * q + 1] + 1e-10f) + 1e-10f;
        float Dv = 0.5f * (T1[a][b] + T2[b][a]) + b3d + __logf(l0 / l1);
        resp[q] = Dv > 0.f ? 1.f : 0.f;
        if (fabsf(Dv) < FLAG_THRESH) {
            unsigned int idx = atomicAdd(&lcnt, 1u);   // LDS atomic
            lflags[idx] = (unsigned int)(ij0 + q);
        }
    }
    *(float4*)&out[ij0] = res;

    // publish lflags; drain main out-stores (vmcnt(0) before s_barrier)
    __syncthreads();

    // ---------------- repair phase (exact f64, per-wave) ----------------
    unsigned int nl = lcnt;
    int lane = tid & 63;
    int wave = tid >> 6;
    double w3dd = (double)W3[lane * 2 + 1] - (double)W3[lane * 2 + 0];
    double b2d = (double)b2[lane];

    for (unsigned int f = wave; f < nl; f += 4) {
        int ij = (int)lflags[f];
        int ii = ij >> 10, jj = ij & (N - 1);
        double uvd = 0.0;
        if (lane < 2) uvd = (double)u[(((size_t)ij) << 1) + lane];
        {   // lane = k (two k's per lane), coalesced f64 loads
            int k0 = lane, k1 = lane + 64;
            double ai0 = A64[(size_t)ii * H1 + k0], ai1 = A64[(size_t)ii * H1 + k1];
            double aj0 = A64[(size_t)jj * H1 + k0], aj1 = A64[(size_t)jj * H1 + k1];
            double bi0 = B64[(size_t)ii * H1 + k0], bi1 = B64[(size_t)ii * H1 + k1];
            double bj0 = B64[(size_t)jj * H1 + k0], bj1 = B64[(size_t)jj * H1 + k1];
            double v;
            v = ai0 + bj0; h1s[wave][0][k0] = v > 0.0 ? v : 0.0;
            v = ai1 + bj1; h1s[wave][0][k1] = v > 0.0 ? v : 0.0;
            v = aj0 + bi0; h1s[wave][1][k0] = v > 0.0 ? v : 0.0;
            v = aj1 + bi1; h1s[wave][1][k1] = v > 0.0 ? v : 0.0;
        }
        asm volatile("s_waitcnt lgkmcnt(0)" ::: "memory");
        __builtin_amdgcn_wave_barrier();

        // 8 independent chains: latency-hides the f64 FMA dep chain
        const double* __restrict__ hap = h1s[wave][0];
        const double* __restrict__ hbp = h1s[wave][1];
        double sa0 = 0.0, sa1 = 0.0, sa2 = 0.0, sa3 = 0.0;
        double sb0 = 0.0, sb1 = 0.0, sb2 = 0.0, sb3 = 0.0;
        #pragma unroll 2
        for (int k = 0; k < H1; k += 4) {
            double w0 = (double)W2[(k + 0) * H2 + lane];
            double w1 = (double)W2[(k + 1) * H2 + lane];
            double w2v = (double)W2[(k + 2) * H2 + lane];
            double w3v = (double)W2[(k + 3) * H2 + lane];
            sa0 += hap[k + 0] * w0;  sa1 += hap[k + 1] * w1;
            sa2 += hap[k + 2] * w2v; sa3 += hap[k + 3] * w3v;
            sb0 += hbp[k + 0] * w0;  sb1 += hbp[k + 1] * w1;
            sb2 += hbp[k + 2] * w2v; sb3 += hbp[k + 3] * w3v;
        }
        double sa = ((sa0 + sa1) + (sa2 + sa3)) + b2d;
        double sb = ((sb0 + sb1) + (sb2 + sb3)) + b2d;
        if (sa < 0.0) sa = 0.0;
        if (sb < 0.0) sb = 0.0;
        double da = sa * w3dd;
        double db = sb * w3dd;
        #pragma unroll
        for (int off = 32; off > 0; off >>= 1) {
            da += __shfl_down(da, off, 64);
            db += __shfl_down(db, off, 64);
        }
        double g = 0.0;
        if (lane < 2) g = -log(-log(uvd + 1e-10) + 1e-10);   // lanes 0,1 in parallel
        double g0 = __shfl(g, 0, 64);
        double g1 = __shfl(g, 1, 64);
        if (lane == 0) {
            double b3dd = (double)b3[1] - (double)b3[0];
            double Dv = 0.5 * (da + db) + b3dd + (g1 - g0);
            out[ij] = Dv > 0.0 ? 1.f : 0.f;
        }
        __builtin_amdgcn_wave_barrier();   // DS in-order per wave; stop reordering
    }
}

// ---------------------------------------------------------------------------
extern "C" void kernel_launch(void* const* d_in, const int* in_sizes, int n_in,
                              void* d_out, int out_size, void* d_ws, size_t ws_size,
                              hipStream_t stream) {
    const float* X  = (const float*)d_in[0];
    const float* W1 = (const float*)d_in[1];
    const float* b1 = (const float*)d_in[2];
    const float* W2 = (const float*)d_in[3];
    const float* b2 = (const float*)d_in[4];
    const float* W3 = (const float*)d_in[5];
    const float* b3 = (const float*)d_in[6];
    const float* u  = (const float*)d_in[7];
    float* out = (float*)d_out;

    // workspace layout (doubles first for alignment)
    double* A64 = (double*)d_ws;                         // 1 MB
    double* B64 = A64 + (size_t)N * H1;                  // 1 MB
    float* dmat = (float*)(B64 + (size_t)N * H1);        // 4 MB
    _Float16* A16 = (_Float16*)(dmat + (size_t)N * N);   // 256 KB
    _Float16* B16 = A16 + (size_t)N * H1;                // 256 KB

    precompute_kernel<<<N, 128, 0, stream>>>(X, W1, b1, A64, B64, A16, B16);
    pair_mlp_kernel<<<(N / 16) * (N / 64), 256, 0, stream>>>(A16, B16, W2, b2, W3, dmat);
    epilogue_repair_kernel<<<(N / 32) * (N / 32), 256, 0, stream>>>(
        dmat, A64, B64, W2, b2, W3, b3, u, out);
}